// Round 1
// baseline (307.523 us; speedup 1.0000x reference)
//
#include <hip/hip_runtime.h>
#include <cstdint>
#include <cstddef>

// Problem constants
#define B_   4
#define L_   1024
#define C_   512
#define H_   8
#define DK_  64
#define DV_  192
#define NF_  192
#define HALF_ 96
#define KE_  256   // extended score inner dim: 64 (Q·K) + 192 (A'·C~)
#define BH_  32    // B*H

typedef _Float16 half8 __attribute__((ext_vector_type(8)));
typedef _Float16 half4v __attribute__((ext_vector_type(4)));
typedef float f32x4 __attribute__((ext_vector_type(4)));

// ---------------- elementwise f32 -> f16 convert (4/thread) ----------------
__global__ void k_f32_to_f16(const float* __restrict__ src, _Float16* __restrict__ dst, int n4) {
    int i = blockIdx.x * 256 + threadIdx.x;
    if (i >= n4) return;
    float4 v = ((const float4*)src)[i];
    half4v h;
    h[0] = (_Float16)v.x; h[1] = (_Float16)v.y; h[2] = (_Float16)v.z; h[3] = (_Float16)v.w;
    ((half4v*)dst)[i] = h;
}

// ---------------- transpose+convert: src[K,N] f32 -> dst[N,K] f16 ----------------
__global__ void k_transpose_f16(const float* __restrict__ src, _Float16* __restrict__ dst, int K, int N) {
    __shared__ float tile[64][65];
    int n0 = blockIdx.x << 6, k0 = blockIdx.y << 6;
    int tid = threadIdx.x;
#pragma unroll
    for (int q = 0; q < 16; ++q) {
        int e = (q << 8) + tid;
        int r = e >> 6, c = e & 63;
        tile[r][c] = src[(size_t)(k0 + r) * N + n0 + c];
    }
    __syncthreads();
#pragma unroll
    for (int q = 0; q < 16; ++q) {
        int e = (q << 8) + tid;
        int r = e >> 6, c = e & 63;
        dst[(size_t)(n0 + r) * K + k0 + c] = (_Float16)tile[c][r];
    }
}

// ---------------- trig tables: Tsin/Tcos[i*96+f] = sin/cos(i * w_f) ----------------
__global__ void k_trig(float* __restrict__ Tsin, float* __restrict__ Tcos) {
    int idx = blockIdx.x * 256 + threadIdx.x;
    if (idx >= L_ * HALF_) return;
    int i = idx / HALF_;
    int f = idx - i * HALF_;
    // ln(10000)/96, rounded to f32 like the reference
    float w = expf(-(float)f * 0.09594104554141865f);
    float a = (float)i * w;
    Tsin[idx] = sinf(a);
    Tcos[idx] = cosf(a);
}

// ---------------- generic fp16 MFMA GEMM: C[M,N] = A[M,K] @ Bt[N,K]^T + bias ----------------
// M multiple of 128, K multiple of 32; N arbitrary (Bt rows >= N zero-padded in LDS).
__global__ __launch_bounds__(256) void k_gemm_f16(
    const _Float16* __restrict__ A, const _Float16* __restrict__ Bt,
    const float* __restrict__ bias, float* __restrict__ C,
    int M, int N, int K)
{
    __shared__ _Float16 As[128][40];
    __shared__ _Float16 Bs[128][40];
    const int tid = threadIdx.x;
    const int m0 = blockIdx.y << 7, n0 = blockIdx.x << 7;
    const int lane = tid & 63, l15 = lane & 15, g = lane >> 4;
    const int w = tid >> 6;
    const int wm = (w >> 1) << 6, wn = (w & 1) << 6;
    const f32x4 zero4 = {0.f, 0.f, 0.f, 0.f};
    f32x4 acc[4][4];
#pragma unroll
    for (int a = 0; a < 4; ++a)
#pragma unroll
        for (int b = 0; b < 4; ++b) acc[a][b] = zero4;

    const int nk = K >> 5;
    for (int kt = 0; kt < nk; ++kt) {
        const int k0 = kt << 5;
        __syncthreads();
#pragma unroll
        for (int q = 0; q < 2; ++q) {
            int c = (q << 8) + tid;
            int row = c >> 2, ch = c & 3;
            *(half8*)(&As[row][ch << 3]) = *(const half8*)(A + (size_t)(m0 + row) * K + k0 + (ch << 3));
        }
#pragma unroll
        for (int q = 0; q < 2; ++q) {
            int c = (q << 8) + tid;
            int row = c >> 2, ch = c & 3;
            half8 val;
            if (n0 + row < N) {
                val = *(const half8*)(Bt + (size_t)(n0 + row) * K + k0 + (ch << 3));
            } else {
                for (int z = 0; z < 8; ++z) val[z] = (_Float16)0.f;
            }
            *(half8*)(&Bs[row][ch << 3]) = val;
        }
        __syncthreads();
        half8 af[4], bf[4];
#pragma unroll
        for (int a = 0; a < 4; ++a) af[a] = *(const half8*)(&As[wm + (a << 4) + l15][g << 3]);
#pragma unroll
        for (int b = 0; b < 4; ++b) bf[b] = *(const half8*)(&Bs[wn + (b << 4) + l15][g << 3]);
#pragma unroll
        for (int a = 0; a < 4; ++a)
#pragma unroll
            for (int b = 0; b < 4; ++b)
                acc[a][b] = __builtin_amdgcn_mfma_f32_16x16x32_f16(af[a], bf[b], acc[a][b], 0, 0, 0);
    }
#pragma unroll
    for (int a = 0; a < 4; ++a)
#pragma unroll
        for (int b = 0; b < 4; ++b)
#pragma unroll
            for (int r = 0; r < 4; ++r) {
                int row = m0 + wm + (a << 4) + (g << 2) + r;
                int col = n0 + wn + (b << 4) + l15;
                if (col < N)
                    C[(size_t)row * N + col] = acc[a][b][r] + (bias ? bias[col] : 0.0f);
            }
}

// ---------------- QVh[(b*8+h)*1024+i][k] = f16(Qf[b*1024+i][h*64+k] + v[h][k]) ----------------
__global__ void k_qvh(const float* __restrict__ Qf, const float* __restrict__ v, _Float16* __restrict__ QVh) {
    int idx = blockIdx.x * 256 + threadIdx.x;       // 0 .. 32768*64-1
    int k = idx & 63, r = idx >> 6;
    int i = r & 1023, h = (r >> 10) & 7, b = r >> 13;
    QVh[idx] = (_Float16)(Qf[((size_t)(b << 10) + i) * 512 + (h << 6) + k] + v[(h << 6) + k]);
}

// ---------------- Qext row build: [Q(64) | A'_sin(96) | A'_cos(96)] ----------------
__global__ void k_qext(const float* __restrict__ Qf, const float* __restrict__ Gf,
                       const float* __restrict__ Tsin, const float* __restrict__ Tcos,
                       _Float16* __restrict__ Qext) {
    int r = blockIdx.x;             // (b,h,i) row
    int t = threadIdx.x;            // 0..255
    int i = r & 1023, h = (r >> 10) & 7, b = r >> 13;
    _Float16 val;
    if (t < 64) {
        val = (_Float16)Qf[((size_t)(b << 10) + i) * 512 + (h << 6) + t];
    } else {
        int f = (t < 160) ? (t - 64) : (t - 160);
        float g0 = Gf[(size_t)r * 192 + f];
        float g1 = Gf[(size_t)r * 192 + 96 + f];
        float s = Tsin[i * 96 + f], c = Tcos[i * 96 + f];
        val = (_Float16)((t < 160) ? (g0 * c + g1 * s) : (g1 * c - g0 * s));
    }
    Qext[(size_t)r * 256 + t] = val;
}

// ---------------- Kext row build: [K(64) | sin_j(96) | cos_j(96)]; bias3 = u_h . K_j ----------------
__global__ void k_kext(const float* __restrict__ Kf, const float* __restrict__ u,
                       const float* __restrict__ Tsin, const float* __restrict__ Tcos,
                       _Float16* __restrict__ Kext, float* __restrict__ bias3) {
    int r = blockIdx.x;
    int t = threadIdx.x;
    int j = r & 1023, h = (r >> 10) & 7, b = r >> 13;
    if (t < 64) {
        float kv = Kf[((size_t)(b << 10) + j) * 512 + (h << 6) + t];
        Kext[(size_t)r * 256 + t] = (_Float16)kv;
        float p = u[(h << 6) + t] * kv;
#pragma unroll
        for (int m = 1; m < 64; m <<= 1) p += __shfl_xor(p, m);
        if (t == 0) bias3[r] = p;
    } else {
        int f = (t < 160) ? (t - 64) : (t - 160);
        float tv = (t < 160) ? Tsin[j * 96 + f] : Tcos[j * 96 + f];
        Kext[(size_t)r * 256 + t] = (_Float16)tv;
    }
}

// ---------------- V pack: Vf[b*1024+j][h*192+d] f32 -> Vd[(bh*192+d)*1024 + j] f16 ----------------
__global__ void k_pack_v(const float* __restrict__ Vf, _Float16* __restrict__ Vd) {
    __shared__ float tile[64][65];
    int j0 = blockIdx.x << 6;       // 16 tiles
    int d0 = blockIdx.y << 6;       // 3 tiles
    int bh = blockIdx.z;            // 32
    int b = bh >> 3, h = bh & 7;
    int tid = threadIdx.x;
#pragma unroll
    for (int q = 0; q < 16; ++q) {
        int e = (q << 8) + tid;
        int r = e >> 6, c = e & 63;
        tile[r][c] = Vf[((size_t)(b << 10) + j0 + r) * 1536 + h * 192 + d0 + c];
    }
    __syncthreads();
#pragma unroll
    for (int q = 0; q < 16; ++q) {
        int e = (q << 8) + tid;
        int r = e >> 6, c = e & 63;  // r = d offset, c = j offset
        Vd[((size_t)bh * 192 + d0 + r) * 1024 + j0 + c] = (_Float16)tile[c][r];
    }
}

// ---------------- fused rel-pos flash attention ----------------
// grid (16 q-tiles, 32 bh); 256 thr = 4 waves; wave handles 16 query rows.
__global__ __launch_bounds__(256) void k_attn(
    const _Float16* __restrict__ Qext, const _Float16* __restrict__ Kext,
    const _Float16* __restrict__ Vd, const float* __restrict__ bias3,
    _Float16* __restrict__ AOh)
{
    __shared__ _Float16 Kt[64][264];   // 33792 B, stride 528 B: 2-way bank aliasing (free)
    __shared__ _Float16 Vt[192][88];   // 33792 B, stride 176 B
    __shared__ _Float16 Pt[64][88];    // 11264 B

    const int bh = blockIdx.y;
    const int i0 = blockIdx.x << 6;
    const int tid = threadIdx.x;
    const int w = tid >> 6, lane = tid & 63, l15 = lane & 15, g = lane >> 4;
    const int b = bh >> 3, h = bh & 7;

    // Q fragments in registers: wave's 16 rows x 256 k
    const _Float16* Qg = Qext + ((size_t)bh * 1024 + i0 + (w << 4) + l15) * 256 + (g << 3);
    half8 qf[8];
#pragma unroll
    for (int kq = 0; kq < 8; ++kq) qf[kq] = *(const half8*)(Qg + (kq << 5));

    const f32x4 zero4 = {0.f, 0.f, 0.f, 0.f};
    f32x4 oacc[12];
#pragma unroll
    for (int dn = 0; dn < 12; ++dn) oacc[dn] = zero4;
    float m_run[4], l_run[4];
#pragma unroll
    for (int r = 0; r < 4; ++r) { m_run[r] = -3.0e38f; l_run[r] = 0.f; }

    const _Float16* Kg = Kext + (size_t)bh * 1024 * 256;
    const _Float16* Vg = Vd + (size_t)bh * 192 * 1024;
    const float* b3g = bias3 + bh * 1024;

    for (int jt = 0; jt < 16; ++jt) {
        const int j0 = jt << 6;
        __syncthreads();
        // stage Kext tile [64][256]
#pragma unroll
        for (int q = 0; q < 8; ++q) {
            int c = (q << 8) + tid;
            int row = c >> 5, ch = c & 31;
            *(half8*)(&Kt[row][ch << 3]) = *(const half8*)(Kg + (size_t)(j0 + row) * 256 + (ch << 3));
        }
        // stage V tile transposed [192][64] (Vd is d-major so reads are contiguous)
#pragma unroll
        for (int q = 0; q < 6; ++q) {
            int c = (q << 8) + tid;
            int d = c >> 3, jc = c & 7;
            *(half8*)(&Vt[d][jc << 3]) = *(const half8*)(Vg + (size_t)d * 1024 + j0 + (jc << 3));
        }
        __syncthreads();

        // S = Qext @ Kext^T   (16 rows x 64 cols per wave)
        f32x4 s[4];
#pragma unroll
        for (int jn = 0; jn < 4; ++jn) s[jn] = zero4;
#pragma unroll
        for (int kq = 0; kq < 8; ++kq) {
#pragma unroll
            for (int jn = 0; jn < 4; ++jn) {
                half8 bf = *(const half8*)(&Kt[(jn << 4) + l15][(kq << 5) + (g << 3)]);
                s[jn] = __builtin_amdgcn_mfma_f32_16x16x32_f16(qf[kq], bf, s[jn], 0, 0, 0);
            }
        }
        // + term3 bias (per key column)
#pragma unroll
        for (int jn = 0; jn < 4; ++jn) {
            float b3 = b3g[j0 + (jn << 4) + l15];
#pragma unroll
            for (int r = 0; r < 4; ++r) s[jn][r] += b3;
        }
        // online softmax (row = (g*4+r); j spread over l15 lanes x 4 jn tiles)
        float alpha[4];
#pragma unroll
        for (int r = 0; r < 4; ++r) {
            float tm = fmaxf(fmaxf(s[0][r], s[1][r]), fmaxf(s[2][r], s[3][r]));
            tm = fmaxf(tm, __shfl_xor(tm, 1));
            tm = fmaxf(tm, __shfl_xor(tm, 2));
            tm = fmaxf(tm, __shfl_xor(tm, 4));
            tm = fmaxf(tm, __shfl_xor(tm, 8));
            float mnew = fmaxf(m_run[r], tm);
            float al = __expf(m_run[r] - mnew);
            float ps = 0.f;
#pragma unroll
            for (int jn = 0; jn < 4; ++jn) {
                float p = __expf(s[jn][r] - mnew);
                s[jn][r] = p;
                ps += p;
            }
            ps += __shfl_xor(ps, 1);
            ps += __shfl_xor(ps, 2);
            ps += __shfl_xor(ps, 4);
            ps += __shfl_xor(ps, 8);
            l_run[r] = l_run[r] * al + ps;
            m_run[r] = mnew;
            alpha[r] = al;
        }
#pragma unroll
        for (int dn = 0; dn < 12; ++dn)
#pragma unroll
            for (int r = 0; r < 4; ++r) oacc[dn][r] *= alpha[r];
        // P -> LDS (accum layout -> A-frag layout)
#pragma unroll
        for (int jn = 0; jn < 4; ++jn)
#pragma unroll
            for (int r = 0; r < 4; ++r)
                Pt[(w << 4) + (g << 2) + r][(jn << 4) + l15] = (_Float16)s[jn][r];
        __syncthreads();
        // O += P @ V
        half8 pa0 = *(const half8*)(&Pt[(w << 4) + l15][(g << 3)]);
        half8 pa1 = *(const half8*)(&Pt[(w << 4) + l15][32 + (g << 3)]);
#pragma unroll
        for (int dn = 0; dn < 12; ++dn) {
            half8 vb0 = *(const half8*)(&Vt[(dn << 4) + l15][(g << 3)]);
            oacc[dn] = __builtin_amdgcn_mfma_f32_16x16x32_f16(pa0, vb0, oacc[dn], 0, 0, 0);
            half8 vb1 = *(const half8*)(&Vt[(dn << 4) + l15][32 + (g << 3)]);
            oacc[dn] = __builtin_amdgcn_mfma_f32_16x16x32_f16(pa1, vb1, oacc[dn], 0, 0, 0);
        }
    }
    // epilogue: normalize, write AOh[b, i, h*192 + d] f16
    float inv[4];
#pragma unroll
    for (int r = 0; r < 4; ++r) inv[r] = 1.0f / l_run[r];
#pragma unroll
    for (int dn = 0; dn < 12; ++dn)
#pragma unroll
        for (int r = 0; r < 4; ++r)
            AOh[((size_t)(b << 10) + i0 + (w << 4) + (g << 2) + r) * 1536 + h * 192 + (dn << 4) + l15]
                = (_Float16)(oacc[dn][r] * inv[r]);
}

// ---------------- host launch ----------------
extern "C" void kernel_launch(void* const* d_in, const int* in_sizes, int n_in,
                              void* d_out, int out_size, void* d_ws, size_t ws_size,
                              hipStream_t stream) {
    const float* x  = (const float*)d_in[0];
    const float* Wq = (const float*)d_in[1];
    const float* bq = (const float*)d_in[2];
    const float* Wk = (const float*)d_in[3];
    const float* bk = (const float*)d_in[4];
    const float* Wv = (const float*)d_in[5];
    const float* bv = (const float*)d_in[6];
    const float* Wo = (const float*)d_in[7];
    const float* bo = (const float*)d_in[8];
    const float* We = (const float*)d_in[9];
    const float* u  = (const float*)d_in[10];
    const float* v  = (const float*)d_in[11];
    float* out = (float*)d_out;

    char* ws = (char*)d_ws;
    size_t off = 0;
    auto alloc = [&](size_t bytes) -> void* {
        void* p = ws + off;
        off += (bytes + 255) & ~(size_t)255;
        return p;
    };
    _Float16* xh   = (_Float16*)alloc((size_t)4096 * 512 * 2);
    _Float16* Wqt  = (_Float16*)alloc((size_t)512 * 512 * 2);
    _Float16* Wkt  = (_Float16*)alloc((size_t)512 * 512 * 2);
    _Float16* Wvt  = (_Float16*)alloc((size_t)1536 * 512 * 2);
    _Float16* Wot  = (_Float16*)alloc((size_t)512 * 1536 * 2);
    _Float16* Weh  = (_Float16*)alloc((size_t)192 * 64 * 2);
    float*    Tsin = (float*)alloc((size_t)1024 * 96 * 4);
    float*    Tcos = (float*)alloc((size_t)1024 * 96 * 4);
    float*    Qf   = (float*)alloc((size_t)4096 * 512 * 4);
    float*    Kf   = (float*)alloc((size_t)4096 * 512 * 4);
    void*     Big  = alloc((size_t)4096 * 1536 * 4);  // Vf f32 -> Gf f32 -> AOh f16 (sequential reuse)
    _Float16* QVh  = (_Float16*)alloc((size_t)32768 * 64 * 2);
    _Float16* Qext = (_Float16*)alloc((size_t)32768 * 256 * 2);
    _Float16* Kext = (_Float16*)alloc((size_t)32768 * 256 * 2);
    float*    bias3 = (float*)alloc((size_t)32768 * 4);
    _Float16* Vd   = (_Float16*)alloc((size_t)32 * 192 * 1024 * 2);
    if (off > ws_size) return;  // insufficient workspace -> clean fail

    float* Vf = (float*)Big;
    float* Gf = (float*)Big;
    _Float16* AOh = (_Float16*)Big;

    // converts / transposes / tables
    k_f32_to_f16<<<2048, 256, 0, stream>>>(x, xh, 4096 * 512 / 4);
    k_f32_to_f16<<<12, 256, 0, stream>>>(We, Weh, 192 * 64 / 4);
    k_transpose_f16<<<dim3(8, 8), 256, 0, stream>>>(Wq, Wqt, 512, 512);
    k_transpose_f16<<<dim3(8, 8), 256, 0, stream>>>(Wk, Wkt, 512, 512);
    k_transpose_f16<<<dim3(24, 8), 256, 0, stream>>>(Wv, Wvt, 512, 1536);
    k_transpose_f16<<<dim3(8, 24), 256, 0, stream>>>(Wo, Wot, 1536, 512);
    k_trig<<<(1024 * 96 + 255) / 256, 256, 0, stream>>>(Tsin, Tcos);

    // projections
    k_gemm_f16<<<dim3(4, 32), 256, 0, stream>>>(xh, Wqt, bq, Qf, 4096, 512, 512);
    k_gemm_f16<<<dim3(4, 32), 256, 0, stream>>>(xh, Wkt, bk, Kf, 4096, 512, 512);
    k_gemm_f16<<<dim3(12, 32), 256, 0, stream>>>(xh, Wvt, bv, Vf, 4096, 1536, 512);
    k_pack_v<<<dim3(16, 3, 32), 256, 0, stream>>>(Vf, Vd);

    // G = (Q + v_h) @ We^T  (rows = (b,h,i))
    k_qvh<<<32768 * 64 / 256, 256, 0, stream>>>(Qf, v, QVh);
    k_gemm_f16<<<dim3(2, 256), 256, 0, stream>>>(QVh, Weh, nullptr, Gf, 32768, 192, 64);

    // extended Q / K + column bias
    k_qext<<<32768, 256, 0, stream>>>(Qf, Gf, Tsin, Tcos, Qext);
    k_kext<<<32768, 256, 0, stream>>>(Kf, u, Tsin, Tcos, Kext, bias3);

    // fused attention
    k_attn<<<dim3(16, 32), 256, 0, stream>>>(Qext, Kext, Vd, bias3, AOh);

    // output projection -> d_out
    k_gemm_f16<<<dim3(4, 32), 256, 0, stream>>>(AOh, Wot, bo, out, 4096, 512, 1536);
}

// Round 2
// 303.556 us; speedup vs baseline: 1.0131x; 1.0131x over previous
//
#include <hip/hip_runtime.h>
#include <cstdint>
#include <cstddef>

// Problem constants
#define B_   4
#define L_   1024
#define H_   8
#define DK_  64
#define DV_  192
#define HALF_ 96

typedef _Float16 half8 __attribute__((ext_vector_type(8)));
typedef _Float16 half4v __attribute__((ext_vector_type(4)));
typedef float f32x4 __attribute__((ext_vector_type(4)));

__device__ __forceinline__ void gll16(const void* g, void* lds) {
    __builtin_amdgcn_global_load_lds(
        (const __attribute__((address_space(1))) unsigned int*)g,
        (__attribute__((address_space(3))) unsigned int*)lds, 16, 0, 0);
}

// ---------------- elementwise f32 -> f16 convert (4/thread) ----------------
__global__ void k_f32_to_f16(const float* __restrict__ src, _Float16* __restrict__ dst, int n4) {
    int i = blockIdx.x * 256 + threadIdx.x;
    if (i >= n4) return;
    float4 v = ((const float4*)src)[i];
    half4v h;
    h[0] = (_Float16)v.x; h[1] = (_Float16)v.y; h[2] = (_Float16)v.z; h[3] = (_Float16)v.w;
    ((half4v*)dst)[i] = h;
}

// ---------------- transpose+convert: src[K,N] f32 -> dst[N,K] f16 ----------------
__global__ void k_transpose_f16(const float* __restrict__ src, _Float16* __restrict__ dst, int K, int N) {
    __shared__ float tile[64][65];
    int n0 = blockIdx.x << 6, k0 = blockIdx.y << 6;
    int tid = threadIdx.x;
#pragma unroll
    for (int q = 0; q < 16; ++q) {
        int e = (q << 8) + tid;
        int r = e >> 6, c = e & 63;
        tile[r][c] = src[(size_t)(k0 + r) * N + n0 + c];
    }
    __syncthreads();
#pragma unroll
    for (int q = 0; q < 16; ++q) {
        int e = (q << 8) + tid;
        int r = e >> 6, c = e & 63;
        dst[(size_t)(n0 + r) * K + k0 + c] = (_Float16)tile[c][r];
    }
}

// ---------------- bias concat bq|bk|bv -> bqkv[2560] ----------------
__global__ void k_concat_bias(const float* __restrict__ bq, const float* __restrict__ bk,
                              const float* __restrict__ bv, float* __restrict__ bqkv) {
    int i = blockIdx.x * 256 + threadIdx.x;
    if (i >= 2560) return;
    float v;
    if (i < 512) v = bq[i];
    else if (i < 1024) v = bk[i - 512];
    else v = bv[i - 1024];
    bqkv[i] = v;
}

// ---------------- trig tables: Tsin/Tcos[i*96+f] = sin/cos(i * w_f) ----------------
__global__ void k_trig(float* __restrict__ Tsin, float* __restrict__ Tcos) {
    int idx = blockIdx.x * 256 + threadIdx.x;
    if (idx >= L_ * HALF_) return;
    int i = idx / HALF_;
    int f = idx - i * HALF_;
    float w = expf(-(float)f * 0.09594104554141865f);   // ln(10000)/96
    float a = (float)i * w;
    Tsin[idx] = sinf(a);
    Tcos[idx] = cosf(a);
}

// ---------------- fp16 MFMA GEMM: C[M,N] = A[M,K] @ Bt[N,K]^T + bias ----------------
// M mult of 128, K mult of 64; N arbitrary. global_load_lds staging, BK=64,
// XOR-swizzled LDS (inverse-swz source + swz read), 32KB LDS -> 5 blocks/CU.
template<bool OUT_F16>
__global__ __launch_bounds__(256) void k_gemm2(
    const _Float16* __restrict__ A, const _Float16* __restrict__ Bt,
    const float* __restrict__ bias, void* __restrict__ Cout,
    int M, int N, int K, int nbx)
{
    __shared__ _Float16 As[128 * 64];
    __shared__ _Float16 Bs[128 * 64];
    const int nwg = gridDim.x;
    const int bid = blockIdx.x;
    const int sw = (bid & 7) * (nwg >> 3) + (bid >> 3);   // XCD-chunked (nwg % 8 == 0)
    const int bx = sw % nbx, by = sw / nbx;
    const int m0 = by << 7, n0 = bx << 7;
    const int tid = threadIdx.x;
    const int lane = tid & 63, l15 = lane & 15, g = lane >> 4;
    const int w = tid >> 6;
    const int wm = (w >> 1) << 6, wn = (w & 1) << 6;
    f32x4 acc[4][4] = {};

    const int nk = K >> 6;
    for (int kt = 0; kt < nk; ++kt) {
        const int k0 = kt << 6;
        __syncthreads();
#pragma unroll
        for (int i = 0; i < 4; ++i) {
            int Ld = (i << 12) + (tid << 4);
            int row = Ld >> 7, bso = Ld & 127;
            int src = bso ^ ((row & 7) << 4);
            gll16((const char*)A + ((size_t)(m0 + row) * K + k0) * 2 + src, (char*)As + Ld);
        }
#pragma unroll
        for (int i = 0; i < 4; ++i) {
            int Ld = (i << 12) + (tid << 4);
            int row = Ld >> 7, bso = Ld & 127;
            int src = bso ^ ((row & 7) << 4);
            int rn = n0 + row; if (rn > N - 1) rn = N - 1;
            gll16((const char*)Bt + ((size_t)rn * K + k0) * 2 + src, (char*)Bs + Ld);
        }
        __syncthreads();
#pragma unroll
        for (int kq = 0; kq < 2; ++kq) {
            half8 af[4], bf[4];
#pragma unroll
            for (int a = 0; a < 4; ++a) {
                int row = wm + (a << 4) + l15;
                int byt = ((kq << 6) + (g << 4)) ^ ((row & 7) << 4);
                af[a] = *(const half8*)((const char*)As + (row << 7) + byt);
            }
#pragma unroll
            for (int b = 0; b < 4; ++b) {
                int row = wn + (b << 4) + l15;
                int byt = ((kq << 6) + (g << 4)) ^ ((row & 7) << 4);
                bf[b] = *(const half8*)((const char*)Bs + (row << 7) + byt);
            }
#pragma unroll
            for (int a = 0; a < 4; ++a)
#pragma unroll
                for (int b = 0; b < 4; ++b)
                    acc[a][b] = __builtin_amdgcn_mfma_f32_16x16x32_f16(af[a], bf[b], acc[a][b], 0, 0, 0);
        }
    }
#pragma unroll
    for (int a = 0; a < 4; ++a)
#pragma unroll
        for (int b = 0; b < 4; ++b)
#pragma unroll
            for (int r = 0; r < 4; ++r) {
                int row = m0 + wm + (a << 4) + (g << 2) + r;
                int col = n0 + wn + (b << 4) + l15;
                if (col < N) {
                    float vv = acc[a][b][r] + (bias ? bias[col] : 0.0f);
                    if (OUT_F16) ((_Float16*)Cout)[(size_t)row * N + col] = (_Float16)vv;
                    else         ((float*)Cout)[(size_t)row * N + col] = vv;
                }
            }
}

// ---------------- QVh[(bh)*1024+i][k] = f16(Qh + v_h) ----------------
__global__ void k_qvh(const _Float16* __restrict__ Qh, const float* __restrict__ v,
                      _Float16* __restrict__ QVh) {
    int idx = blockIdx.x * 256 + threadIdx.x;       // 0 .. 32768*64-1
    int k = idx & 63, r = idx >> 6;
    int i = r & 1023, h = (r >> 10) & 7, b = r >> 13;
    QVh[idx] = (_Float16)((float)Qh[((size_t)(b << 10) + i) * 2560 + (h << 6) + k] + v[(h << 6) + k]);
}

// ---------------- Qext row build: [Q(64) | A'_sin(96) | A'_cos(96)] ----------------
__global__ void k_qext(const _Float16* __restrict__ Qh, const _Float16* __restrict__ Gf,
                       const float* __restrict__ Tsin, const float* __restrict__ Tcos,
                       _Float16* __restrict__ Qext) {
    int r = blockIdx.x;             // (b,h,i) row
    int t = threadIdx.x;            // 0..255
    int i = r & 1023, h = (r >> 10) & 7, b = r >> 13;
    _Float16 val;
    if (t < 64) {
        val = Qh[((size_t)(b << 10) + i) * 2560 + (h << 6) + t];
    } else {
        int f = (t < 160) ? (t - 64) : (t - 160);
        float g0 = (float)Gf[(size_t)r * 192 + f];
        float g1 = (float)Gf[(size_t)r * 192 + 96 + f];
        float s = Tsin[i * 96 + f], c = Tcos[i * 96 + f];
        val = (_Float16)((t < 160) ? (g0 * c + g1 * s) : (g1 * c - g0 * s));
    }
    Qext[(size_t)r * 256 + t] = val;
}

// ---------------- Kext row build + bias3 = u_h . K_j ----------------
__global__ void k_kext(const _Float16* __restrict__ Kh, const float* __restrict__ u,
                       const float* __restrict__ Tsin, const float* __restrict__ Tcos,
                       _Float16* __restrict__ Kext, float* __restrict__ bias3) {
    int r = blockIdx.x;
    int t = threadIdx.x;
    int j = r & 1023, h = (r >> 10) & 7, b = r >> 13;
    if (t < 64) {
        float kv = (float)Kh[((size_t)(b << 10) + j) * 2560 + 512 + (h << 6) + t];
        Kext[(size_t)r * 256 + t] = (_Float16)kv;
        float p = u[(h << 6) + t] * kv;
#pragma unroll
        for (int m = 1; m < 64; m <<= 1) p += __shfl_xor(p, m);
        if (t == 0) bias3[r] = p;
    } else {
        int f = (t < 160) ? (t - 64) : (t - 160);
        float tv = (t < 160) ? Tsin[j * 96 + f] : Tcos[j * 96 + f];
        Kext[(size_t)r * 256 + t] = (_Float16)tv;
    }
}

// ---------------- V pack: QKVh[.,1024+h*192+d] f16 -> Vd[(bh*192+d)*1024 + j] ----------------
__global__ void k_pack_v(const _Float16* __restrict__ Vh, _Float16* __restrict__ Vd) {
    __shared__ float tile[64][65];
    int j0 = blockIdx.x << 6;       // 16
    int d0 = blockIdx.y << 6;       // 3
    int bh = blockIdx.z;            // 32
    int b = bh >> 3, h = bh & 7;
    int tid = threadIdx.x;
#pragma unroll
    for (int q = 0; q < 16; ++q) {
        int e = (q << 8) + tid;
        int r = e >> 6, c = e & 63;
        tile[r][c] = (float)Vh[((size_t)(b << 10) + j0 + r) * 2560 + 1024 + h * 192 + d0 + c];
    }
    __syncthreads();
#pragma unroll
    for (int q = 0; q < 16; ++q) {
        int e = (q << 8) + tid;
        int r = e >> 6, c = e & 63;  // r = d offset, c = j offset
        Vd[((size_t)bh * 192 + d0 + r) * 1024 + j0 + c] = (_Float16)tile[c][r];
    }
}

// ---------------- fused rel-pos flash attention v2 ----------------
// 512 blocks (XCD-swizzled: 4 bh per XCD -> K/V L2-resident), 256 thr = 4 waves.
// Wave = 32 q-rows (a=2) x one j-half (8 of 16 KV tiles). No K/V LDS staging:
// B-fragments read straight from L2. Wave-private swizzled P tile (no barriers
// in main loop). End: (m,l,O) combine across j-halves through LDS.
__global__ __launch_bounds__(256, 2) void k_attn(
    const _Float16* __restrict__ Qext, const _Float16* __restrict__ Kext,
    const _Float16* __restrict__ Vd, const float* __restrict__ bias3,
    _Float16* __restrict__ AOh)
{
    __shared__ char smem[51200];

    const int bid = blockIdx.x;
    const int sw = ((bid & 7) << 6) + (bid >> 3);   // 64 blocks per XCD chunk
    const int bh = sw >> 4;
    const int i0 = (sw & 15) << 6;
    const int tid = threadIdx.x;
    const int w = tid >> 6, lane = tid & 63, l15 = lane & 15, g = lane >> 4;
    const int rowg = w & 1, jhalf = w >> 1;
    const int b = bh >> 3, h = bh & 7;

    _Float16* Pt = (_Float16*)(smem + (w << 12));   // wave-private 4KB [32 rows][128B]

    // Q fragments in registers: 32 rows x 256 k
    const _Float16* Qg = Qext + (((size_t)bh << 10)) * 256;
    half8 qf[2][8];
#pragma unroll
    for (int a = 0; a < 2; ++a) {
        const _Float16* qp = Qg + (size_t)(i0 + (rowg << 5) + (a << 4) + l15) * 256 + (g << 3);
#pragma unroll
        for (int kq = 0; kq < 8; ++kq) qf[a][kq] = *(const half8*)(qp + (kq << 5));
    }

    f32x4 oacc[2][12] = {};
    float m_run[2][4], l_run[2][4];
#pragma unroll
    for (int a = 0; a < 2; ++a)
#pragma unroll
        for (int r = 0; r < 4; ++r) { m_run[a][r] = -3.0e38f; l_run[a][r] = 0.f; }

    const _Float16* Kg = Kext + (((size_t)bh << 10)) * 256;
    const _Float16* Vg = Vd + (size_t)bh * 192 * 1024;
    const float* b3g = bias3 + (bh << 10);

    for (int it = 0; it < 8; ++it) {
        const int j0 = ((jhalf << 3) + it) << 6;
        // S = Qext @ Kext^T  (32 rows x 64 cols per wave), K-frags from L2
        f32x4 s[2][4] = {};
#pragma unroll
        for (int kq = 0; kq < 8; ++kq) {
#pragma unroll
            for (int jn = 0; jn < 4; ++jn) {
                half8 bf = *(const half8*)(Kg + (size_t)(j0 + (jn << 4) + l15) * 256 + (kq << 5) + (g << 3));
                s[0][jn] = __builtin_amdgcn_mfma_f32_16x16x32_f16(qf[0][kq], bf, s[0][jn], 0, 0, 0);
                s[1][jn] = __builtin_amdgcn_mfma_f32_16x16x32_f16(qf[1][kq], bf, s[1][jn], 0, 0, 0);
            }
        }
        // + term3 column bias
#pragma unroll
        for (int jn = 0; jn < 4; ++jn) {
            float b3 = b3g[j0 + (jn << 4) + l15];
#pragma unroll
            for (int a = 0; a < 2; ++a)
#pragma unroll
                for (int r = 0; r < 4; ++r) s[a][jn][r] += b3;
        }
        // online softmax; j spread over l15 lanes x 4 jn tiles
#pragma unroll
        for (int a = 0; a < 2; ++a) {
#pragma unroll
            for (int r = 0; r < 4; ++r) {
                float tm = fmaxf(fmaxf(s[a][0][r], s[a][1][r]), fmaxf(s[a][2][r], s[a][3][r]));
                tm = fmaxf(tm, __shfl_xor(tm, 1));
                tm = fmaxf(tm, __shfl_xor(tm, 2));
                tm = fmaxf(tm, __shfl_xor(tm, 4));
                tm = fmaxf(tm, __shfl_xor(tm, 8));
                float mnew = fmaxf(m_run[a][r], tm);
                float al = __expf(m_run[a][r] - mnew);
                float ps = 0.f;
#pragma unroll
                for (int jn = 0; jn < 4; ++jn) {
                    float p = __expf(s[a][jn][r] - mnew);
                    s[a][jn][r] = p;
                    ps += p;
                }
                ps += __shfl_xor(ps, 1);
                ps += __shfl_xor(ps, 2);
                ps += __shfl_xor(ps, 4);
                ps += __shfl_xor(ps, 8);
                l_run[a][r] = l_run[a][r] * al + ps;
                m_run[a][r] = mnew;
#pragma unroll
                for (int dn = 0; dn < 12; ++dn) oacc[a][dn][r] *= al;
            }
        }
        // P -> wave-private LDS, swizzle slot ^= (row&7)^((row>>2)&2)  (2-way, free)
#pragma unroll
        for (int a = 0; a < 2; ++a)
#pragma unroll
            for (int jn = 0; jn < 4; ++jn)
#pragma unroll
                for (int r = 0; r < 4; ++r) {
                    int row = (a << 4) + (g << 2) + r;
                    int byt = (((jn << 4) + l15) << 1) ^ (((row & 7) ^ ((row >> 2) & 2)) << 4);
                    *(_Float16*)((char*)Pt + (row << 7) + byt) = (_Float16)s[a][jn][r];
                }
        // read back P fragments (same-wave: lgkmcnt only, no barrier)
        half8 pa[2][2];
#pragma unroll
        for (int a = 0; a < 2; ++a)
#pragma unroll
            for (int kq = 0; kq < 2; ++kq) {
                int row = (a << 4) + l15;
                int byt = ((kq << 6) + (g << 4)) ^ (((row & 7) ^ ((row >> 2) & 2)) << 4);
                pa[a][kq] = *(const half8*)((const char*)Pt + (row << 7) + byt);
            }
        // O += P @ V  (V^T frags from L2)
#pragma unroll
        for (int dn = 0; dn < 12; ++dn) {
#pragma unroll
            for (int kq = 0; kq < 2; ++kq) {
                half8 vb = *(const half8*)(Vg + (size_t)((dn << 4) + l15) * 1024 + j0 + (kq << 5) + (g << 3));
                oacc[0][dn] = __builtin_amdgcn_mfma_f32_16x16x32_f16(pa[0][kq], vb, oacc[0][dn], 0, 0, 0);
                oacc[1][dn] = __builtin_amdgcn_mfma_f32_16x16x32_f16(pa[1][kq], vb, oacc[1][dn], 0, 0, 0);
            }
        }
    }

    // ---- combine the two j-halves ----
    __syncthreads();                       // everyone done with Pt
    float* Cml = (float*)smem;             // [2 jhalf][64 rows][m,l]
    float* Co  = (float*)(smem + 1024);    // [64][196] f32 partial O
#pragma unroll
    for (int a = 0; a < 2; ++a)
#pragma unroll
        for (int r = 0; r < 4; ++r)
            if (l15 == 0) {
                int rowi = (rowg << 5) + (a << 4) + (g << 2) + r;
                Cml[(((jhalf << 6) + rowi) << 1) + 0] = m_run[a][r];
                Cml[(((jhalf << 6) + rowi) << 1) + 1] = l_run[a][r];
            }
    __syncthreads();
    float fs[2][4], lt[2][4];
#pragma unroll
    for (int a = 0; a < 2; ++a)
#pragma unroll
        for (int r = 0; r < 4; ++r) {
            int rowi = (rowg << 5) + (a << 4) + (g << 2) + r;
            float mo = Cml[((((1 - jhalf) << 6) + rowi) << 1) + 0];
            float lo = Cml[((((1 - jhalf) << 6) + rowi) << 1) + 1];
            float M = fmaxf(m_run[a][r], mo);
            float f0 = __expf(m_run[a][r] - M);
            float f1 = __expf(mo - M);
            fs[a][r] = f0;
            lt[a][r] = l_run[a][r] * f0 + lo * f1;
        }
    if (jhalf == 1) {
#pragma unroll
        for (int a = 0; a < 2; ++a)
#pragma unroll
            for (int dn = 0; dn < 12; ++dn)
#pragma unroll
                for (int r = 0; r < 4; ++r) {
                    int rowi = (rowg << 5) + (a << 4) + (g << 2) + r;
                    Co[rowi * 196 + (dn << 4) + l15] = oacc[a][dn][r] * fs[a][r];
                }
    }
    __syncthreads();
    if (jhalf == 0) {
#pragma unroll
        for (int a = 0; a < 2; ++a)
#pragma unroll
            for (int r = 0; r < 4; ++r) {
                int rowi = (rowg << 5) + (a << 4) + (g << 2) + r;
                float inv = 1.0f / lt[a][r];
#pragma unroll
                for (int dn = 0; dn < 12; ++dn) {
                    float ov = (oacc[a][dn][r] * fs[a][r] + Co[rowi * 196 + (dn << 4) + l15]) * inv;
                    AOh[((size_t)(b << 10) + i0 + rowi) * 1536 + h * 192 + (dn << 4) + l15] = (_Float16)ov;
                }
            }
    }
}

// ---------------- host launch ----------------
extern "C" void kernel_launch(void* const* d_in, const int* in_sizes, int n_in,
                              void* d_out, int out_size, void* d_ws, size_t ws_size,
                              hipStream_t stream) {
    const float* x  = (const float*)d_in[0];
    const float* Wq = (const float*)d_in[1];
    const float* bq = (const float*)d_in[2];
    const float* Wk = (const float*)d_in[3];
    const float* bk = (const float*)d_in[4];
    const float* Wv = (const float*)d_in[5];
    const float* bv = (const float*)d_in[6];
    const float* Wo = (const float*)d_in[7];
    const float* bo = (const float*)d_in[8];
    const float* We = (const float*)d_in[9];
    const float* u  = (const float*)d_in[10];
    const float* v  = (const float*)d_in[11];
    float* out = (float*)d_out;

    char* ws = (char*)d_ws;
    size_t off = 0;
    auto alloc = [&](size_t bytes) -> void* {
        void* p = ws + off;
        off += (bytes + 255) & ~(size_t)255;
        return p;
    };
    _Float16* xh    = (_Float16*)alloc((size_t)4096 * 512 * 2);
    _Float16* Weh   = (_Float16*)alloc((size_t)192 * 64 * 2);
    _Float16* Wqkvt = (_Float16*)alloc((size_t)2560 * 512 * 2);
    _Float16* Wot   = (_Float16*)alloc((size_t)512 * 1536 * 2);
    float*    bqkv  = (float*)alloc((size_t)2560 * 4);
    float*    Tsin  = (float*)alloc((size_t)1024 * 96 * 4);
    float*    Tcos  = (float*)alloc((size_t)1024 * 96 * 4);
    _Float16* QKVh  = (_Float16*)alloc((size_t)4096 * 2560 * 2);
    _Float16* QVh   = (_Float16*)alloc((size_t)32768 * 64 * 2);
    _Float16* Gf16  = (_Float16*)alloc((size_t)32768 * 192 * 2);
    _Float16* Qext  = (_Float16*)alloc((size_t)32768 * 256 * 2);
    _Float16* Kext  = (_Float16*)alloc((size_t)32768 * 256 * 2);
    float*    bias3 = (float*)alloc((size_t)32768 * 4);
    _Float16* Vd    = (_Float16*)alloc((size_t)32 * 192 * 1024 * 2);
    _Float16* AOh   = (_Float16*)alloc((size_t)4096 * 1536 * 2);
    if (off > ws_size) return;  // insufficient workspace -> clean fail

    // converts / transposes / tables
    k_f32_to_f16<<<2048, 256, 0, stream>>>(x, xh, 4096 * 512 / 4);
    k_f32_to_f16<<<12, 256, 0, stream>>>(We, Weh, 192 * 64 / 4);
    k_transpose_f16<<<dim3(8, 8), 256, 0, stream>>>(Wq, Wqkvt, 512, 512);
    k_transpose_f16<<<dim3(8, 8), 256, 0, stream>>>(Wk, Wqkvt + (size_t)512 * 512, 512, 512);
    k_transpose_f16<<<dim3(24, 8), 256, 0, stream>>>(Wv, Wqkvt + (size_t)1024 * 512, 512, 1536);
    k_transpose_f16<<<dim3(8, 24), 256, 0, stream>>>(Wo, Wot, 1536, 512);
    k_concat_bias<<<10, 256, 0, stream>>>(bq, bk, bv, bqkv);
    k_trig<<<(1024 * 96 + 255) / 256, 256, 0, stream>>>(Tsin, Tcos);

    // fused QKV projection (f16 out): [4096,2560] = xh @ Wqkvt^T + bqkv
    k_gemm2<true><<<640, 256, 0, stream>>>(xh, Wqkvt, bqkv, QKVh, 4096, 2560, 512, 20);

    // G = (Q + v_h) @ We^T  (f16 out)
    k_qvh<<<32768 * 64 / 256, 256, 0, stream>>>(QKVh, v, QVh);
    k_gemm2<true><<<512, 256, 0, stream>>>(QVh, Weh, nullptr, Gf16, 32768, 192, 64, 2);

    // extended Q / K + column bias; V pack
    k_qext<<<32768, 256, 0, stream>>>(QKVh, Gf16, Tsin, Tcos, Qext);
    k_kext<<<32768, 256, 0, stream>>>(QKVh, u, Tsin, Tcos, Kext, bias3);
    k_pack_v<<<dim3(16, 3, 32), 256, 0, stream>>>(QKVh, Vd);

    // fused attention
    k_attn<<<512, 256, 0, stream>>>(Qext, Kext, Vd, bias3, AOh);

    // output projection -> d_out (f32)
    k_gemm2<false><<<128, 256, 0, stream>>>(AOh, Wot, bo, out, 4096, 512, 1536, 4);
}

// Round 3
// 196.149 us; speedup vs baseline: 1.5678x; 1.5476x over previous
//
#include <hip/hip_runtime.h>
#include <cstdint>
#include <cstddef>

// Problem constants
#define B_   4
#define L_   1024
#define H_   8
#define DK_  64
#define DV_  192
#define HALF_ 96

typedef _Float16 half8 __attribute__((ext_vector_type(8)));
typedef _Float16 half4v __attribute__((ext_vector_type(4)));
typedef float f32x4 __attribute__((ext_vector_type(4)));

__device__ __forceinline__ void gll16(const void* g, void* lds) {
    __builtin_amdgcn_global_load_lds(
        (const __attribute__((address_space(1))) unsigned int*)g,
        (__attribute__((address_space(3))) unsigned int*)lds, 16, 0, 0);
}

// ---------------- elementwise f32 -> f16 convert (4/thread) ----------------
__global__ void k_f32_to_f16(const float* __restrict__ src, _Float16* __restrict__ dst, int n4) {
    int i = blockIdx.x * 256 + threadIdx.x;
    if (i >= n4) return;
    float4 v = ((const float4*)src)[i];
    half4v h;
    h[0] = (_Float16)v.x; h[1] = (_Float16)v.y; h[2] = (_Float16)v.z; h[3] = (_Float16)v.w;
    ((half4v*)dst)[i] = h;
}

// ---------------- transpose+convert: src[K,N] f32 -> dst[N,K] f16 ----------------
__global__ void k_transpose_f16(const float* __restrict__ src, _Float16* __restrict__ dst, int K, int N) {
    __shared__ float tile[64][65];
    int n0 = blockIdx.x << 6, k0 = blockIdx.y << 6;
    int tid = threadIdx.x;
#pragma unroll
    for (int q = 0; q < 16; ++q) {
        int e = (q << 8) + tid;
        int r = e >> 6, c = e & 63;
        tile[r][c] = src[(size_t)(k0 + r) * N + n0 + c];
    }
    __syncthreads();
#pragma unroll
    for (int q = 0; q < 16; ++q) {
        int e = (q << 8) + tid;
        int r = e >> 6, c = e & 63;
        dst[(size_t)(n0 + r) * K + k0 + c] = (_Float16)tile[c][r];
    }
}

// ---------------- bias concat bq|bk|bv -> bqkv[2560] ----------------
__global__ void k_concat_bias(const float* __restrict__ bq, const float* __restrict__ bk,
                              const float* __restrict__ bv, float* __restrict__ bqkv) {
    int i = blockIdx.x * 256 + threadIdx.x;
    if (i >= 2560) return;
    float v;
    if (i < 512) v = bq[i];
    else if (i < 1024) v = bk[i - 512];
    else v = bv[i - 1024];
    bqkv[i] = v;
}

// ---------------- trig tables: Tsin/Tcos[i*96+f] = sin/cos(i * w_f) ----------------
__global__ void k_trig(float* __restrict__ Tsin, float* __restrict__ Tcos) {
    int idx = blockIdx.x * 256 + threadIdx.x;
    if (idx >= L_ * HALF_) return;
    int i = idx / HALF_;
    int f = idx - i * HALF_;
    float w = expf(-(float)f * 0.09594104554141865f);   // ln(10000)/96
    float a = (float)i * w;
    Tsin[idx] = sinf(a);
    Tcos[idx] = cosf(a);
}

// ---------------- fp16 MFMA GEMM: C[M,TNB*nbx] = A[M,K] @ Bt[N,K]^T + bias ----------------
// Double-buffered (T3-minimum 2-phase): issue next-tile global_load_lds before
// compute, single __syncthreads per K-tile (its implicit vmcnt(0) is the drain).
// Shapes exact multiples: M%128==0, N%TNB==0, K%64==0.
template<int TNB, bool OUT_F16>
__global__ __launch_bounds__(256) void k_gemm2(
    const _Float16* __restrict__ A, const _Float16* __restrict__ Bt,
    const float* __restrict__ bias, void* __restrict__ Cout,
    int M, int N, int K, int nbx)
{
    constexpr int BUFSZ = 16384 + TNB * 128;
    __shared__ char sm[2 * BUFSZ];
    const int nwg = gridDim.x;
    const int bid = blockIdx.x;
    const int sw = (bid & 7) * (nwg >> 3) + (bid >> 3);   // XCD-chunked (nwg % 8 == 0)
    const int bx = sw % nbx, by = sw / nbx;
    const int m0 = by << 7, n0 = bx * TNB;
    const int tid = threadIdx.x;
    const int lane = tid & 63, l15 = lane & 15, g = lane >> 4;
    const int w = tid >> 6;
    constexpr int AM = (TNB == 128) ? 4 : 2;
    const int wm = (TNB == 128) ? ((w >> 1) << 6) : (w << 5);
    const int wn = (TNB == 128) ? ((w & 1) << 6) : 0;

    f32x4 acc[AM][4] = {};

    auto stage = [&](int kt, int bufsel) {
        char* As = sm + bufsel * BUFSZ;
        char* Bs = As + 16384;
        const char* Ag = (const char*)A + ((size_t)m0 * K + (kt << 6)) * 2;
#pragma unroll
        for (int i2 = 0; i2 < 4; ++i2) {
            int byte = (i2 << 12) + (tid << 4);
            int row = byte >> 7, bso = byte & 127;
            gll16(Ag + (size_t)row * (K * 2) + (bso ^ ((row & 7) << 4)), As + byte);
        }
        const char* Bg = (const char*)Bt + ((size_t)n0 * K + (kt << 6)) * 2;
#pragma unroll
        for (int i2 = 0; i2 < (TNB >> 5); ++i2) {
            int byte = (i2 << 12) + (tid << 4);
            int row = byte >> 7, bso = byte & 127;
            gll16(Bg + (size_t)row * (K * 2) + (bso ^ ((row & 7) << 4)), Bs + byte);
        }
    };

    const int nk = K >> 6;
    stage(0, 0);
    __syncthreads();
    for (int kt = 0; kt < nk; ++kt) {
        const int cur = kt & 1;
        if (kt + 1 < nk) stage(kt + 1, cur ^ 1);
        const char* As = sm + cur * BUFSZ;
        const char* Bs = As + 16384;
#pragma unroll
        for (int kq = 0; kq < 2; ++kq) {
            half8 af[AM], bf[4];
#pragma unroll
            for (int a = 0; a < AM; ++a) {
                int row = wm + (a << 4) + l15;
                af[a] = *(const half8*)(As + (row << 7) + ((((kq << 2) | g) ^ (row & 7)) << 4));
            }
#pragma unroll
            for (int bj = 0; bj < 4; ++bj) {
                int row = wn + (bj << 4) + l15;
                bf[bj] = *(const half8*)(Bs + (row << 7) + ((((kq << 2) | g) ^ (row & 7)) << 4));
            }
#pragma unroll
            for (int a = 0; a < AM; ++a)
#pragma unroll
                for (int bj = 0; bj < 4; ++bj)
                    acc[a][bj] = __builtin_amdgcn_mfma_f32_16x16x32_f16(af[a], bf[bj], acc[a][bj], 0, 0, 0);
        }
        __syncthreads();
    }
#pragma unroll
    for (int a = 0; a < AM; ++a)
#pragma unroll
        for (int bj = 0; bj < 4; ++bj)
#pragma unroll
            for (int r = 0; r < 4; ++r) {
                int row = m0 + wm + (a << 4) + (g << 2) + r;
                int col = n0 + wn + (bj << 4) + l15;
                float vv = acc[a][bj][r] + (bias ? bias[col] : 0.0f);
                if (OUT_F16) ((_Float16*)Cout)[(size_t)row * N + col] = (_Float16)vv;
                else         ((float*)Cout)[(size_t)row * N + col] = vv;
            }
}

// ---------------- QVh[(bh)*1024+i][k] = f16(Qh + v_h), half8 per thread ----------------
__global__ void k_qvh(const _Float16* __restrict__ Qh, const float* __restrict__ v,
                      _Float16* __restrict__ QVh) {
    int t = blockIdx.x * 256 + threadIdx.x;     // 262144 threads
    int k8 = (t & 7) << 3, r = t >> 3;
    int i = r & 1023, h = (r >> 10) & 7, b = r >> 13;
    half8 q = *(const half8*)(Qh + ((size_t)(b << 10) + i) * 2560 + (h << 6) + k8);
    float4 v0 = *(const float4*)(v + (h << 6) + k8);
    float4 v1 = *(const float4*)(v + (h << 6) + k8 + 4);
    float vv[8] = {v0.x, v0.y, v0.z, v0.w, v1.x, v1.y, v1.z, v1.w};
    half8 o;
#pragma unroll
    for (int z = 0; z < 8; ++z) o[z] = (_Float16)((float)q[z] + vv[z]);
    ((half8*)QVh)[t] = o;
}

// ---------------- Qext build: [Q(64) | A'_sin(96) | A'_cos(96)], SWIZZLED storage ----------------
// Row r stored pre-swizzled: 16B-chunk cc lands at byte r*512 + ((cc ^ (r&7))<<4).
__global__ void k_qext(const _Float16* __restrict__ Qh, const _Float16* __restrict__ Gf,
                       const float* __restrict__ Tsin, const float* __restrict__ Tcos,
                       _Float16* __restrict__ Qext) {
    int t = threadIdx.x;
    int r = (blockIdx.x << 3) + (t >> 5);
    int cc = t & 31;
    int i = r & 1023, h = (r >> 10) & 7, b = r >> 13;
    half8 val;
    if (cc < 8) {
        val = *(const half8*)(Qh + ((size_t)(b << 10) + i) * 2560 + (h << 6) + (cc << 3));
    } else {
        int f = (cc < 20) ? ((cc - 8) << 3) : ((cc - 20) << 3);
        half8 g0 = *(const half8*)(Gf + (size_t)r * 192 + f);
        half8 g1 = *(const half8*)(Gf + (size_t)r * 192 + 96 + f);
        float4 s0 = *(const float4*)(Tsin + i * 96 + f);
        float4 s1 = *(const float4*)(Tsin + i * 96 + f + 4);
        float4 c0 = *(const float4*)(Tcos + i * 96 + f);
        float4 c1 = *(const float4*)(Tcos + i * 96 + f + 4);
        float sv[8] = {s0.x, s0.y, s0.z, s0.w, s1.x, s1.y, s1.z, s1.w};
        float cv[8] = {c0.x, c0.y, c0.z, c0.w, c1.x, c1.y, c1.z, c1.w};
        if (cc < 20) {
#pragma unroll
            for (int z = 0; z < 8; ++z) val[z] = (_Float16)((float)g0[z] * cv[z] + (float)g1[z] * sv[z]);
        } else {
#pragma unroll
            for (int z = 0; z < 8; ++z) val[z] = (_Float16)((float)g1[z] * cv[z] - (float)g0[z] * sv[z]);
        }
    }
    *(half8*)((char*)Qext + (size_t)r * 512 + ((cc ^ (r & 7)) << 4)) = val;
}

// ---------------- Kext build + bias3 = u_h . K_j, SWIZZLED storage ----------------
__global__ void k_kext(const _Float16* __restrict__ Kh, const float* __restrict__ u,
                       const float* __restrict__ Tsin, const float* __restrict__ Tcos,
                       _Float16* __restrict__ Kext, float* __restrict__ bias3) {
    int t = threadIdx.x;
    int r = (blockIdx.x << 3) + (t >> 5);
    int cc = t & 31;
    int j = r & 1023, h = (r >> 10) & 7, b = r >> 13;
    half8 val;
    if (cc < 8) {
        val = *(const half8*)(Kh + ((size_t)(b << 10) + j) * 2560 + 512 + (h << 6) + (cc << 3));
        float4 u0 = *(const float4*)(u + (h << 6) + (cc << 3));
        float4 u1 = *(const float4*)(u + (h << 6) + (cc << 3) + 4);
        float p = (float)val[0] * u0.x + (float)val[1] * u0.y + (float)val[2] * u0.z + (float)val[3] * u0.w
                + (float)val[4] * u1.x + (float)val[5] * u1.y + (float)val[6] * u1.z + (float)val[7] * u1.w;
        p += __shfl_xor(p, 1); p += __shfl_xor(p, 2); p += __shfl_xor(p, 4);
        if (cc == 0) bias3[r] = p;
    } else {
        int f = (cc < 20) ? ((cc - 8) << 3) : ((cc - 20) << 3);
        const float* T = (cc < 20) ? Tsin : Tcos;
        float4 t0 = *(const float4*)(T + j * 96 + f);
        float4 t1 = *(const float4*)(T + j * 96 + f + 4);
        float tv[8] = {t0.x, t0.y, t0.z, t0.w, t1.x, t1.y, t1.z, t1.w};
#pragma unroll
        for (int z = 0; z < 8; ++z) val[z] = (_Float16)tv[z];
    }
    *(half8*)((char*)Kext + (size_t)r * 512 + ((cc ^ (r & 7)) << 4)) = val;
}

// ---------------- V pack: Vh -> Vd[(bh*192+d)*1024 + j], per-64j-block SWIZZLED ----------------
__global__ void k_pack_v(const _Float16* __restrict__ Vh, _Float16* __restrict__ Vd) {
    __shared__ _Float16 tile[64][73];
    int j0 = blockIdx.x << 6, d0 = blockIdx.y << 6, bh = blockIdx.z;
    int b = bh >> 3, h = bh & 7;
    int t = threadIdx.x;
#pragma unroll
    for (int q = 0; q < 2; ++q) {
        int e = (q << 8) + t;            // 0..511
        int jr = e >> 3, dc = (e & 7) << 3;
        *(half8*)&tile[jr][dc] = *(const half8*)(Vh + ((size_t)(b << 10) + j0 + jr) * 2560 + 1024 + h * 192 + d0 + dc);
    }
    __syncthreads();
#pragma unroll
    for (int q = 0; q < 2; ++q) {
        int e = (q << 8) + t;
        int dr = e >> 3, jc = e & 7;     // dr 0..63, jc = 16B chunk (8 j)
        half8 v;
#pragma unroll
        for (int z = 0; z < 8; ++z) v[z] = tile[(jc << 3) + z][dr];
        *(half8*)((char*)Vd + (((size_t)bh * 192 + d0 + dr) * 1024 + j0) * 2 + ((jc ^ (dr & 7)) << 4)) = v;
    }
}

// ---------------- fused rel-pos flash attention v3 ----------------
// 256 blocks (1/CU, XCD-chunked: 4 bh per XCD -> K/V L2-resident), 4 waves,
// wave = 32 q-rows, block = 128 q-rows. K_ext+V tiles double-buffered in LDS via
// global_load_lds (pre-swizzled global layouts -> conflict-free ds_read_b128).
// One __syncthreads per KV tile (implicit vmcnt(0) drains the prefetch).
__global__ __launch_bounds__(256, 1) void k_attn(
    const _Float16* __restrict__ Qext, const _Float16* __restrict__ Kext,
    const _Float16* __restrict__ Vd, const float* __restrict__ bias3,
    _Float16* __restrict__ AOh)
{
    __shared__ char smem[131072];    // K0|V0 (57344) + K1|V1 (57344) + P 4x4096

    const int bid = blockIdx.x;
    const int sw = ((bid & 7) << 5) + (bid >> 3);   // 32 blocks per XCD chunk
    const int bh = sw >> 3;
    const int i0 = (sw & 7) << 7;
    const int tid = threadIdx.x;
    const int w = tid >> 6, lane = tid & 63, l15 = lane & 15, g = lane >> 4;
    const int b = bh >> 3, h = bh & 7;

    const char* Kg = (const char*)Kext + ((size_t)bh << 10) * 512;
    const char* Vg = (const char*)Vd + (size_t)bh * 192 * 2048;
    const float* b3g = bias3 + (bh << 10);
    char* P = smem + 114688 + (w << 12);

    // Q fragments in registers (swizzled global layout)
    half8 qf[2][8];
#pragma unroll
    for (int a = 0; a < 2; ++a) {
        int row = i0 + (w << 5) + (a << 4) + l15;
        const char* qp = (const char*)Qext + ((size_t)(bh << 10) + row) * 512;
#pragma unroll
        for (int kq = 0; kq < 8; ++kq)
            qf[a][kq] = *(const half8*)(qp + ((((kq << 2) + g) ^ (row & 7)) << 4));
    }

    f32x4 oacc[2][12] = {};
    float m_run[2][4], l_run[2][4];
#pragma unroll
    for (int a = 0; a < 2; ++a)
#pragma unroll
        for (int r = 0; r < 4; ++r) { m_run[a][r] = -3.0e38f; l_run[a][r] = 0.f; }

    auto stage = [&](int jt, int bufsel) {
        char* Kb = smem + bufsel * 57344;
        char* Vb = Kb + 32768;
        const char* Ksrc = Kg + (size_t)(jt << 6) * 512;
#pragma unroll
        for (int i2 = 0; i2 < 8; ++i2) {
            int byte = (i2 << 12) + (tid << 4);
            gll16(Ksrc + byte, Kb + byte);
        }
        const char* Vsrc = Vg + (size_t)(jt << 7);
#pragma unroll
        for (int i2 = 0; i2 < 6; ++i2) {
            int byte = (i2 << 12) + (tid << 4);
            int d = byte >> 7, seg = byte & 127;
            gll16(Vsrc + (size_t)d * 2048 + seg, Vb + byte);
        }
    };

    stage(0, 0);
    __syncthreads();

    for (int jt = 0; jt < 16; ++jt) {
        const int cur = jt & 1;
        if (jt + 1 < 16) stage(jt + 1, cur ^ 1);
        const char* Kb = smem + cur * 57344;
        const char* Vb = Kb + 32768;
        const int j0 = jt << 6;

        // S = Qext @ Kext^T  (32 rows x 64 cols per wave)
        f32x4 s[2][4] = {};
#pragma unroll
        for (int kq = 0; kq < 8; ++kq) {
#pragma unroll
            for (int jn = 0; jn < 4; ++jn) {
                int row = (jn << 4) + l15;
                half8 bf = *(const half8*)(Kb + (row << 9) + ((((kq << 2) + g) ^ (row & 7)) << 4));
                s[0][jn] = __builtin_amdgcn_mfma_f32_16x16x32_f16(qf[0][kq], bf, s[0][jn], 0, 0, 0);
                s[1][jn] = __builtin_amdgcn_mfma_f32_16x16x32_f16(qf[1][kq], bf, s[1][jn], 0, 0, 0);
            }
        }
        // + term3 column bias
#pragma unroll
        for (int jn = 0; jn < 4; ++jn) {
            float b3 = b3g[j0 + (jn << 4) + l15];
#pragma unroll
            for (int a = 0; a < 2; ++a)
#pragma unroll
                for (int r = 0; r < 4; ++r) s[a][jn][r] += b3;
        }
        // online softmax
#pragma unroll
        for (int a = 0; a < 2; ++a) {
#pragma unroll
            for (int r = 0; r < 4; ++r) {
                float tm = fmaxf(fmaxf(s[a][0][r], s[a][1][r]), fmaxf(s[a][2][r], s[a][3][r]));
                tm = fmaxf(tm, __shfl_xor(tm, 1));
                tm = fmaxf(tm, __shfl_xor(tm, 2));
                tm = fmaxf(tm, __shfl_xor(tm, 4));
                tm = fmaxf(tm, __shfl_xor(tm, 8));
                float mnew = fmaxf(m_run[a][r], tm);
                float al = __expf(m_run[a][r] - mnew);
                float ps = 0.f;
#pragma unroll
                for (int jn = 0; jn < 4; ++jn) {
                    float p = __expf(s[a][jn][r] - mnew);
                    s[a][jn][r] = p;
                    ps += p;
                }
                ps += __shfl_xor(ps, 1);
                ps += __shfl_xor(ps, 2);
                ps += __shfl_xor(ps, 4);
                ps += __shfl_xor(ps, 8);
                l_run[a][r] = l_run[a][r] * al + ps;
                m_run[a][r] = mnew;
#pragma unroll
                for (int dn = 0; dn < 12; ++dn) oacc[a][dn][r] *= al;
            }
        }
        // P -> wave-private LDS (swizzled chunks: col-chunk ^ row&7)
#pragma unroll
        for (int a = 0; a < 2; ++a)
#pragma unroll
            for (int jn = 0; jn < 4; ++jn)
#pragma unroll
                for (int r = 0; r < 4; ++r) {
                    int row = (a << 4) + (g << 2) + r;
                    int col = (jn << 4) + l15;
                    *(_Float16*)(P + (row << 7) + ((col << 1) ^ ((row & 7) << 4))) = (_Float16)s[a][jn][r];
                }
        // P A-frags back (same wave, no barrier)
        half8 pa[2][2];
#pragma unroll
        for (int a = 0; a < 2; ++a)
#pragma unroll
            for (int kq = 0; kq < 2; ++kq) {
                int row = (a << 4) + l15;
                pa[a][kq] = *(const half8*)(P + (row << 7) + ((((kq << 2) + g) ^ (row & 7)) << 4));
            }
        // O += P @ V
#pragma unroll
        for (int dn = 0; dn < 12; ++dn) {
#pragma unroll
            for (int kq = 0; kq < 2; ++kq) {
                int d = (dn << 4) + l15;
                half8 vb = *(const half8*)(Vb + (d << 7) + ((((kq << 2) + g) ^ (d & 7)) << 4));
                oacc[0][dn] = __builtin_amdgcn_mfma_f32_16x16x32_f16(pa[0][kq], vb, oacc[0][dn], 0, 0, 0);
                oacc[1][dn] = __builtin_amdgcn_mfma_f32_16x16x32_f16(pa[1][kq], vb, oacc[1][dn], 0, 0, 0);
            }
        }
        __syncthreads();
    }

    // epilogue: normalize, write AOh[b, i, h*192 + d] f16
#pragma unroll
    for (int a = 0; a < 2; ++a)
#pragma unroll
        for (int r = 0; r < 4; ++r) {
            float inv = 1.0f / l_run[a][r];
            int rowi = i0 + (w << 5) + (a << 4) + (g << 2) + r;
#pragma unroll
            for (int dn = 0; dn < 12; ++dn)
                AOh[((size_t)(b << 10) + rowi) * 1536 + h * 192 + (dn << 4) + l15]
                    = (_Float16)(oacc[a][dn][r] * inv);
        }
}

// ---------------- host launch ----------------
extern "C" void kernel_launch(void* const* d_in, const int* in_sizes, int n_in,
                              void* d_out, int out_size, void* d_ws, size_t ws_size,
                              hipStream_t stream) {
    const float* x  = (const float*)d_in[0];
    const float* Wq = (const float*)d_in[1];
    const float* bq = (const float*)d_in[2];
    const float* Wk = (const float*)d_in[3];
    const float* bk = (const float*)d_in[4];
    const float* Wv = (const float*)d_in[5];
    const float* bv = (const float*)d_in[6];
    const float* Wo = (const float*)d_in[7];
    const float* bo = (const float*)d_in[8];
    const float* We = (const float*)d_in[9];
    const float* u  = (const float*)d_in[10];
    const float* v  = (const float*)d_in[11];
    float* out = (float*)d_out;

    char* ws = (char*)d_ws;
    size_t off = 0;
    auto alloc = [&](size_t bytes) -> void* {
        void* p = ws + off;
        off += (bytes + 255) & ~(size_t)255;
        return p;
    };
    _Float16* xh    = (_Float16*)alloc((size_t)4096 * 512 * 2);
    _Float16* Weh   = (_Float16*)alloc((size_t)192 * 64 * 2);
    _Float16* Wqkvt = (_Float16*)alloc((size_t)2560 * 512 * 2);
    _Float16* Wot   = (_Float16*)alloc((size_t)512 * 1536 * 2);
    float*    bqkv  = (float*)alloc((size_t)2560 * 4);
    float*    Tsin  = (float*)alloc((size_t)1024 * 96 * 4);
    float*    Tcos  = (float*)alloc((size_t)1024 * 96 * 4);
    _Float16* QKVh  = (_Float16*)alloc((size_t)4096 * 2560 * 2);
    _Float16* QVh   = (_Float16*)alloc((size_t)32768 * 64 * 2);
    _Float16* Gf16  = (_Float16*)alloc((size_t)32768 * 192 * 2);
    _Float16* Qext  = (_Float16*)alloc((size_t)32768 * 256 * 2);
    _Float16* Kext  = (_Float16*)alloc((size_t)32768 * 256 * 2);
    float*    bias3 = (float*)alloc((size_t)32768 * 4);
    _Float16* Vd    = (_Float16*)alloc((size_t)32 * 192 * 1024 * 2);
    _Float16* AOh   = (_Float16*)alloc((size_t)4096 * 1536 * 2);
    if (off > ws_size) return;  // insufficient workspace -> clean fail

    // converts / transposes / tables
    k_f32_to_f16<<<2048, 256, 0, stream>>>(x, xh, 4096 * 512 / 4);
    k_f32_to_f16<<<12, 256, 0, stream>>>(We, Weh, 192 * 64 / 4);
    k_transpose_f16<<<dim3(8, 8), 256, 0, stream>>>(Wq, Wqkvt, 512, 512);
    k_transpose_f16<<<dim3(8, 8), 256, 0, stream>>>(Wk, Wqkvt + (size_t)512 * 512, 512, 512);
    k_transpose_f16<<<dim3(24, 8), 256, 0, stream>>>(Wv, Wqkvt + (size_t)1024 * 512, 512, 1536);
    k_transpose_f16<<<dim3(8, 24), 256, 0, stream>>>(Wo, Wot, 1536, 512);
    k_concat_bias<<<10, 256, 0, stream>>>(bq, bk, bv, bqkv);
    k_trig<<<(1024 * 96 + 255) / 256, 256, 0, stream>>>(Tsin, Tcos);

    // fused QKV projection (f16 out): [4096,2560] = xh @ Wqkvt^T + bqkv
    k_gemm2<128, true><<<640, 256, 0, stream>>>(xh, Wqkvt, bqkv, QKVh, 4096, 2560, 512, 20);

    // G = (Q + v_h) @ We^T  (f16 out)
    k_qvh<<<1024, 256, 0, stream>>>(QKVh, v, QVh);
    k_gemm2<64, true><<<768, 256, 0, stream>>>(QVh, Weh, nullptr, Gf16, 32768, 192, 64, 3);

    // extended Q / K (swizzled) + column bias; V pack (swizzled)
    k_qext<<<4096, 256, 0, stream>>>(QKVh, Gf16, Tsin, Tcos, Qext);
    k_kext<<<4096, 256, 0, stream>>>(QKVh, u, Tsin, Tcos, Kext, bias3);
    k_pack_v<<<dim3(16, 3, 32), 256, 0, stream>>>(QKVh, Vd);

    // fused attention
    k_attn<<<256, 256, 0, stream>>>(Qext, Kext, Vd, bias3, AOh);

    // output projection -> d_out (f32)
    k_gemm2<64, false><<<256, 256, 0, stream>>>(AOh, Wot, bo, out, 4096, 512, 1536, 8);
}